// Round 3
// baseline (432.642 us; speedup 1.0000x reference)
//
#include <hip/hip_runtime.h>
#include <hip/hip_bf16.h>

#define D_MODEL 768
#define NH 12
#define DK 64
#define RQ 6
#define RK 2
#define RV 2
#define BATCH 8
#define SEQ 4096
#define NPOS (BATCH*SEQ)

typedef _Float16 v8h __attribute__((ext_vector_type(8)));
typedef float v4f __attribute__((ext_vector_type(4)));

// Async global->LDS DMA, 16B per lane. LDS dest is wave-uniform base + lane*16
// (we pass per-thread base + t*16, which satisfies that by construction).
#define GLDS16(ldst, gsrc)                                                     \
    __builtin_amdgcn_global_load_lds(                                          \
        (const __attribute__((address_space(1))) void*)(unsigned long long)    \
            (const void*)(gsrc),                                               \
        (__attribute__((address_space(3))) void*)(unsigned int)                \
            (unsigned long long)(void*)(ldst),                                 \
        16, 0, 0)

// ---------------------------------------------------------------------------
// Repack (fp32 -> fp16): WcatT[n][k] = concat-weights transposed, bcat[n] fp32;
// WoT[n][k] = Wo[k][n]. n in [760,768) zero-padded.
// ---------------------------------------------------------------------------
__global__ __launch_bounds__(256) void repack(
    const float* __restrict__ Waq, const float* __restrict__ baq,
    const float* __restrict__ Wbq, const float* __restrict__ bbq,
    const float* __restrict__ Wak, const float* __restrict__ bak,
    const float* __restrict__ Wbk, const float* __restrict__ bbk,
    const float* __restrict__ Wav, const float* __restrict__ bav,
    const float* __restrict__ Wbv, const float* __restrict__ bbv,
    const float* __restrict__ Wo,
    _Float16* __restrict__ WcatT, _Float16* __restrict__ WoT,
    float* __restrict__ bcat)
{
    const int n = blockIdx.x;   // 0..767
    const int t = threadIdx.x;
    const float* W = nullptr; const float* bsrc = nullptr;
    int cols = 0, col = 0;
    if      (n <  72) { W=Waq; bsrc=baq; cols=72;  col=n;     }
    else if (n < 456) { W=Wbq; bsrc=bbq; cols=384; col=n-72;  }
    else if (n < 480) { W=Wak; bsrc=bak; cols=24;  col=n-456; }
    else if (n < 608) { W=Wbk; bsrc=bbk; cols=128; col=n-480; }
    else if (n < 632) { W=Wav; bsrc=bav; cols=24;  col=n-608; }
    else if (n < 760) { W=Wbv; bsrc=bbv; cols=128; col=n-632; }
    for (int k = t; k < 768; k += 256) {
        WcatT[(size_t)n*768 + k] = W ? (_Float16)W[(size_t)k*cols + col] : (_Float16)0.f;
        WoT[(size_t)n*768 + k]   = (_Float16)Wo[(size_t)k*768 + n];
    }
    if (t == 0) bcat[n] = W ? bsrc[col] : 0.f;
}

// ---------------------------------------------------------------------------
// x fp32 -> fp16, vectorized (2x float4 in, 1x v8h out per iter).
// Output lives in the O workspace region (dead until tpa_attn_f writes it).
// ---------------------------------------------------------------------------
__global__ __launch_bounds__(256) void convert_x(
    const float4* __restrict__ x, v8h* __restrict__ xh)
{
    const int nth = gridDim.x * 256;
    for (int i = blockIdx.x*256 + threadIdx.x; i < NPOS*96; i += nth) {
        float4 a = x[2*(size_t)i];
        float4 b = x[2*(size_t)i + 1];
        v8h h;
        h[0]=(_Float16)a.x; h[1]=(_Float16)a.y; h[2]=(_Float16)a.z; h[3]=(_Float16)a.w;
        h[4]=(_Float16)b.x; h[5]=(_Float16)b.y; h[6]=(_Float16)b.z; h[7]=(_Float16)b.w;
        xh[i] = h;
    }
}

// ---------------------------------------------------------------------------
// MFMA GEMM, 3-buffer depth-2 pipeline (T3+T4): C(Mx768) = A @ BT^T + bias.
// 128x128 tile, BK=32, 4 waves, 4x4 mfma_f32_16x16x32_f16 per wave.
// Steady state per phase T: issue STAGE(tile T+2 -> buf (T+2)%3), wait
// vmcnt(8) (drains ONLY tile T's 4 loads; 8 newer loads stay in flight
// across the barriers), compute buf T%3. Loads are issued ~2 phases before
// consumption -> covers ~900cy HBM-miss latency. Fully unrolled rotation
// (x3 body + peeled tail) so all buffer indices are compile-time.
// ---------------------------------------------------------------------------
template<int MODE>
__global__ __launch_bounds__(256, 3) void mfma_gemm(
    const _Float16* __restrict__ A,
    const _Float16* __restrict__ BT,
    const float* __restrict__ bias,
    const float* __restrict__ rope,
    float* __restrict__ C)
{
    const int t = threadIdx.x;
    const int lane = t & 63;
    const int wave = t >> 6;

    // XCD-aware swizzle of the 1536-block grid (6 x 256)
    const int flat = blockIdx.y * 6 + blockIdx.x;
    const int xcd = flat & 7;
    const int sub = flat >> 3;          // 0..191
    const int ct  = sub % 6;
    const int rt  = xcd * 32 + sub / 6; // 0..255
    const int row0 = rt * 128;
    const int col0 = ct * 128;

    const int wrow = (wave >> 1) * 64;
    const int wcol = (wave & 1) * 64;

    __shared__ v8h As[3][512];   // [buf][kc 0..3][row 0..127], linear (DMA dest)
    __shared__ v8h Bs[3][512];

    v4f acc[4][4];
    #pragma unroll
    for (int i = 0; i < 4; ++i)
        #pragma unroll
        for (int j = 0; j < 4; ++j)
            acc[i][j] = (v4f){0.f, 0.f, 0.f, 0.f};

    const v8h* gA = (const v8h*)A;     // row stride 96 chunks
    const v8h* gB = (const v8h*)BT;    // row stride 96 chunks

    // staging decomposition: thread t covers (kc = t>>7, row = t&127)
    const int r  = t & 127;
    const int kc = t >> 7;             // 0 or 1; +2 handled by second issue
    const size_t gaBase = (size_t)(row0 + r)*96 + kc;
    const size_t gbBase = (size_t)(col0 + r)*96 + kc;

    const int q = lane >> 4;   // k-chunk for fragments
    const int m = lane & 15;

#define STAGE(buf, kchunk)                                                     \
    do {                                                                       \
        char* la_ = (char*)(&As[buf][0]) + t*16;                               \
        char* lb_ = (char*)(&Bs[buf][0]) + t*16;                               \
        GLDS16(la_,        gA + gaBase + (kchunk));                            \
        GLDS16(la_ + 4096, gA + gaBase + (kchunk) + 2);                        \
        GLDS16(lb_,        gB + gbBase + (kchunk));                            \
        GLDS16(lb_ + 4096, gB + gbBase + (kchunk) + 2);                        \
    } while (0)

#define COMPUTE(buf)                                                           \
    do {                                                                       \
        v8h af[4], bf[4];                                                      \
        _Pragma("unroll")                                                      \
        for (int mi = 0; mi < 4; ++mi)                                         \
            af[mi] = As[buf][q*128 + wrow + mi*16 + m];                        \
        _Pragma("unroll")                                                      \
        for (int ni = 0; ni < 4; ++ni)                                         \
            bf[ni] = Bs[buf][q*128 + wcol + ni*16 + m];                        \
        __builtin_amdgcn_s_setprio(1);                                         \
        _Pragma("unroll")                                                      \
        for (int mi = 0; mi < 4; ++mi)                                         \
            _Pragma("unroll")                                                  \
            for (int ni = 0; ni < 4; ++ni)                                     \
                acc[mi][ni] = __builtin_amdgcn_mfma_f32_16x16x32_f16(          \
                    af[mi], bf[ni], acc[mi][ni], 0, 0, 0);                     \
        __builtin_amdgcn_s_setprio(0);                                         \
    } while (0)

#define PHASE(cbuf, sbuf, kchunk)                                              \
    do {                                                                       \
        STAGE(sbuf, kchunk);                                                   \
        asm volatile("s_waitcnt vmcnt(8)" ::: "memory");                       \
        __builtin_amdgcn_s_barrier();                                          \
        asm volatile("" ::: "memory");                                         \
        COMPUTE(cbuf);                                                         \
        asm volatile("" ::: "memory");                                         \
        __builtin_amdgcn_s_barrier();                                          \
    } while (0)

    // prologue: tiles 0,1 into bufs 0,1 (8 loads in flight)
    STAGE(0, 0);
    STAGE(1, 4);

    // tiles 0..20 in triples; tile T computes buf T%3, stages tile T+2
    for (int i = 0; i < 7; ++i) {
        const int kc0 = i * 12;
        PHASE(0, 2, kc0 + 8);    // T=3i
        PHASE(1, 0, kc0 + 12);   // T=3i+1
        PHASE(2, 1, kc0 + 16);   // T=3i+2
    }
    // peeled tail: T=21 (stages last tile 23), T=22, T=23
    PHASE(0, 2, 92);                                  // T=21
    asm volatile("s_waitcnt vmcnt(4)" ::: "memory");  // T=22: drain tile 22
    __builtin_amdgcn_s_barrier();
    asm volatile("" ::: "memory");
    COMPUTE(1);
    asm volatile("" ::: "memory");
    __builtin_amdgcn_s_barrier();
    asm volatile("s_waitcnt vmcnt(0)" ::: "memory");  // T=23: drain tile 23
    __builtin_amdgcn_s_barrier();
    asm volatile("" ::: "memory");
    COMPUTE(2);

#undef PHASE
#undef STAGE
#undef COMPUTE

    // Epilogue. C/D layout: col = lane&15, row = (lane>>4)*4 + reg.
    #pragma unroll
    for (int mi = 0; mi < 4; ++mi) {
        #pragma unroll
        for (int i = 0; i < 4; ++i) {
            const int grow = row0 + wrow + mi*16 + q*4 + i;
            #pragma unroll
            for (int ni = 0; ni < 4; ++ni) {
                const int gcol = col0 + wcol + ni*16 + m;
                float v = acc[mi][ni][i] + bias[gcol];
                if (MODE == 0) {
                    const int s = grow & 4095;
                    if (gcol >= 72 && gcol < 456)
                        v *= rope[s*64 + ((gcol - 72) & 63)];
                    else if (gcol >= 480 && gcol < 608)
                        v *= rope[s*64 + ((gcol - 480) & 63)];
                }
                C[(size_t)grow*768 + gcol] = v;
            }
        }
    }
}

// ---------------------------------------------------------------------------
// Factorized per-position attention (rope already in P).
//   G[r,r'] = (bq_r . bk_r')/8          (6x2 Gram)
//   scores[h,g] = sum_r aq[r,h] * (G[r,0]ak[0,g] + G[r,1]ak[1,g])
//   attn = softmax_g(scores)
//   c[h,r'] = sum_g attn[h,g] av[r',g]
//   out[h,d] = c[h,0] bv[0,d] + c[h,1] bv[1,d]
// Never materializes Q/K/V. 8 positions per 256-thread block. O fp16,
// layout [b][h][s][d] (flat == transpose(0,2,1,3).reshape view).
// ---------------------------------------------------------------------------
__global__ __launch_bounds__(256) void tpa_attn_f(
    const float* __restrict__ P,
    _Float16* __restrict__ O)
{
    const int t = threadIdx.x;
    const int pos0 = blockIdx.x * 8;

    __shared__ float proj[8][772];   // row pad 768->772: de-bank positions
    __shared__ float Gs[8][12];
    __shared__ float sc[8][160];     // 12 rows x stride 13
    __shared__ float cs[8][24];

    // load 8 P-rows (float4)
    const float4* gp = (const float4*)P;
    for (int i = t; i < 8*192; i += 256) {
        int p = i / 192, c = i - p*192;
        float4 u = gp[(size_t)(pos0 + p)*192 + c];
        proj[p][c*4+0] = u.x; proj[p][c*4+1] = u.y;
        proj[p][c*4+2] = u.z; proj[p][c*4+3] = u.w;
    }
    __syncthreads();

    // Gram matrix: 8 pos x 12 (r,r') pairs
    if (t < 96) {
        int p = t / 12, u = t - (t/12)*12, r = u >> 1, r2 = u & 1;
        const float* bq = &proj[p][72  + r*64];
        const float* bk = &proj[p][480 + r2*64];
        const int ph = (r*8 + r2*16) & 63;   // stagger start to spread banks
        float acc = 0.f;
        for (int i = 0; i < 64; ++i) {
            int d = (i + ph) & 63;
            acc = fmaf(bq[d], bk[d], acc);
        }
        Gs[p][u] = acc * 0.125f;
    }
    __syncthreads();

    // scores: 8 pos x 144 (h,g)
    for (int i = t; i < 8*144; i += 256) {
        int p = i / 144, v = i - p*144, h = v / 12, g = v - (v/12)*12;
        float s = 0.f;
        #pragma unroll
        for (int r = 0; r < RQ; ++r) {
            float mg = fmaf(Gs[p][r*2+1], proj[p][468 + g],
                            Gs[p][r*2+0] * proj[p][456 + g]);
            s = fmaf(proj[p][r*12 + h], mg, s);
        }
        sc[p][h*13 + g] = s;
    }
    __syncthreads();

    // softmax over g: 96 rows
    if (t < 96) {
        int p = t / 12, h = t - (t/12)*12;
        float* row = &sc[p][h*13];
        float mx = -1e30f;
        #pragma unroll
        for (int g = 0; g < NH; ++g) mx = fmaxf(mx, row[g]);
        float sum = 0.f;
        #pragma unroll
        for (int g = 0; g < NH; ++g) { float e = __expf(row[g]-mx); row[g] = e; sum += e; }
        float inv = 1.0f / sum;
        #pragma unroll
        for (int g = 0; g < NH; ++g) row[g] *= inv;
    }
    __syncthreads();

    // c[h,r'] = attn . av^T : 8 pos x 24
    if (t < 192) {
        int p = t / 24, u = t - (t/24)*24, h = u >> 1, r2 = u & 1;
        float acc = 0.f;
        #pragma unroll
        for (int g = 0; g < NH; ++g)
            acc = fmaf(sc[p][h*13+g], proj[p][608 + r2*12 + g], acc);
        cs[p][h*2 + r2] = acc;
    }
    __syncthreads();

    // out: 8 pos x 768, d fastest for coalesced fp16 stores
    for (int i = t; i < 8*768; i += 256) {
        int p = i / 768, j = i - p*768, h = j >> 6, d = j & 63;
        int pos = pos0 + p, b = pos >> 12, s = pos & 4095;
        float val = fmaf(cs[p][h*2+1], proj[p][632 + 64 + d],
                         cs[p][h*2+0] * proj[p][632 + d]);
        O[(((size_t)b*NH + h)*SEQ + s)*DK + d] = (_Float16)val;
    }
}

extern "C" void kernel_launch(void* const* d_in, const int* in_sizes, int n_in,
                              void* d_out, int out_size, void* d_ws, size_t ws_size,
                              hipStream_t stream) {
    const float* x    = (const float*)d_in[0];
    const float* rope = (const float*)d_in[1];
    const float* Waq  = (const float*)d_in[2];
    const float* baq  = (const float*)d_in[3];
    const float* Wbq  = (const float*)d_in[4];
    const float* bbq  = (const float*)d_in[5];
    const float* Wak  = (const float*)d_in[6];
    const float* bak  = (const float*)d_in[7];
    const float* Wbk  = (const float*)d_in[8];
    const float* bbk  = (const float*)d_in[9];
    const float* Wav  = (const float*)d_in[10];
    const float* bav  = (const float*)d_in[11];
    const float* Wbv  = (const float*)d_in[12];
    const float* bbv  = (const float*)d_in[13];
    const float* Wo   = (const float*)d_in[14];
    const float* bo   = (const float*)d_in[15];

    // ws layout (total ~52.7 MB): fp16 weights + fp16 O
    char* ws = (char*)d_ws;
    _Float16* WcatT = (_Float16*)(ws);                 // 1,179,648 B
    _Float16* WoT   = (_Float16*)(ws + 1179648);       // 1,179,648 B
    float*    bcat  = (float*)(ws + 2359296);          // 3,072 B
    _Float16* O     = (_Float16*)(ws + 2363392);       // 50,331,648 B

    // P (fp32, 32768x768 = exactly out_size floats) lives in d_out; fully
    // consumed by tpa_attn_f before the final GEMM overwrites d_out.
    float* P = (float*)d_out;

    // Xh (fp16 x, 48 MB) time-shares the O region: written here, fully
    // consumed by mfma_gemm<0>, then overwritten by tpa_attn_f's O.
    _Float16* Xh = O;

    repack<<<768, 256, 0, stream>>>(Waq, baq, Wbq, bbq, Wak, bak, Wbk, bbk,
                                    Wav, bav, Wbv, bbv, Wo, WcatT, WoT, bcat);

    convert_x<<<1024, 256, 0, stream>>>((const float4*)x, (v8h*)Xh);

    dim3 gg(6, 256);
    mfma_gemm<0><<<gg, 256, 0, stream>>>(Xh, WcatT, bcat, rope, P);

    tpa_attn_f<<<NPOS/8, 256, 0, stream>>>(P, O);

    mfma_gemm<1><<<gg, 256, 0, stream>>>(O, WoT, bo, nullptr, (float*)d_out);
}

// Round 4
// 419.326 us; speedup vs baseline: 1.0318x; 1.0318x over previous
//
#include <hip/hip_runtime.h>
#include <hip/hip_bf16.h>

#define D_MODEL 768
#define NH 12
#define DK 64
#define RQ 6
#define RK 2
#define RV 2
#define BATCH 8
#define SEQ 4096
#define NPOS (BATCH*SEQ)

typedef _Float16 v8h __attribute__((ext_vector_type(8)));
typedef float v4f __attribute__((ext_vector_type(4)));

// Async global->LDS DMA, 16B per lane. LDS dest is wave-uniform base + lane*16.
#define GLDS16(ldst, gsrc)                                                     \
    __builtin_amdgcn_global_load_lds(                                          \
        (const __attribute__((address_space(1))) void*)(unsigned long long)    \
            (const void*)(gsrc),                                               \
        (__attribute__((address_space(3))) void*)(unsigned int)                \
            (unsigned long long)(void*)(ldst),                                 \
        16, 0, 0)

// ---------------------------------------------------------------------------
// Repack (fp32 -> fp16): WcatT[n][k] = concat-weights transposed, bcat[n] fp32;
// WoT[n][k] = Wo[k][n]. n in [760,768) zero-padded.
// ---------------------------------------------------------------------------
__global__ __launch_bounds__(256) void repack(
    const float* __restrict__ Waq, const float* __restrict__ baq,
    const float* __restrict__ Wbq, const float* __restrict__ bbq,
    const float* __restrict__ Wak, const float* __restrict__ bak,
    const float* __restrict__ Wbk, const float* __restrict__ bbk,
    const float* __restrict__ Wav, const float* __restrict__ bav,
    const float* __restrict__ Wbv, const float* __restrict__ bbv,
    const float* __restrict__ Wo,
    _Float16* __restrict__ WcatT, _Float16* __restrict__ WoT,
    float* __restrict__ bcat)
{
    const int n = blockIdx.x;   // 0..767
    const int t = threadIdx.x;
    const float* W = nullptr; const float* bsrc = nullptr;
    int cols = 0, col = 0;
    if      (n <  72) { W=Waq; bsrc=baq; cols=72;  col=n;     }
    else if (n < 456) { W=Wbq; bsrc=bbq; cols=384; col=n-72;  }
    else if (n < 480) { W=Wak; bsrc=bak; cols=24;  col=n-456; }
    else if (n < 608) { W=Wbk; bsrc=bbk; cols=128; col=n-480; }
    else if (n < 632) { W=Wav; bsrc=bav; cols=24;  col=n-608; }
    else if (n < 760) { W=Wbv; bsrc=bbv; cols=128; col=n-632; }
    for (int k = t; k < 768; k += 256) {
        WcatT[(size_t)n*768 + k] = W ? (_Float16)W[(size_t)k*cols + col] : (_Float16)0.f;
        WoT[(size_t)n*768 + k]   = (_Float16)Wo[(size_t)k*768 + n];
    }
    if (t == 0) bcat[n] = W ? bsrc[col] : 0.f;
}

// ---------------------------------------------------------------------------
// x fp32 -> fp16, vectorized (2x float4 in, 1x v8h out per iter).
// ---------------------------------------------------------------------------
__global__ __launch_bounds__(256) void convert_x(
    const float4* __restrict__ x, v8h* __restrict__ xh)
{
    const int nth = gridDim.x * 256;
    for (int i = blockIdx.x*256 + threadIdx.x; i < NPOS*96; i += nth) {
        float4 a = x[2*(size_t)i];
        float4 b = x[2*(size_t)i + 1];
        v8h h;
        h[0]=(_Float16)a.x; h[1]=(_Float16)a.y; h[2]=(_Float16)a.z; h[3]=(_Float16)a.w;
        h[4]=(_Float16)b.x; h[5]=(_Float16)b.y; h[6]=(_Float16)b.z; h[7]=(_Float16)b.w;
        xh[i] = h;
    }
}

// ---------------------------------------------------------------------------
// MFMA GEMM, 8-phase 256x256 schedule (T3+T4+T5): C(Mx768) = A @ BT^T + bias.
// BK=64, 8 waves (2M x 4N), per-wave output 128x64 (8x4 frags of 16x16).
// LDS: per operand 4 k-half slots of 16KB (256 rows x 4 v8h k-chunks);
// slot for [tile T, k-half kc] = (2T+kc)%4. Per K-tile, 4 sub-phases:
//   ph1: read A m0-3 + B n0-3 (k0) | stage [T+1,k1].A | bar | 16 MFMA | bar
//   ph2: read A m4-7 (k0)          | stage [T+1,k1].B | bar | 16 MFMA | vmcnt(6) | bar
//   ph3: read A m0-3 + B n0-3 (k1) | stage [T+2,k0].A | bar | 16 MFMA | bar
//   ph4: read A m4-7 (k1)          | stage [T+2,k0].B | bar | 16 MFMA | vmcnt(6) | bar
// vmcnt(6) = 3 half-tiles (2 loads/wave each) in flight, never 0 in the main
// loop; every stage targets a slot whose readers finished >=1 barrier earlier.
// ---------------------------------------------------------------------------
#define VMCNT(n) asm volatile("s_waitcnt vmcnt(" #n ")" ::: "memory")
#define BAR() do { asm volatile("" ::: "memory");                              \
                   __builtin_amdgcn_s_barrier();                               \
                   asm volatile("" ::: "memory"); } while (0)

template<int MODE>
__global__ __launch_bounds__(512, 2) void mfma_gemm(
    const _Float16* __restrict__ A,
    const _Float16* __restrict__ BT,
    const float* __restrict__ bias,
    const float* __restrict__ rope,
    float* __restrict__ C)
{
    const int t = threadIdx.x;          // 0..511
    const int lane = t & 63;
    const int wave = t >> 6;            // 0..7
    const int wm = wave >> 2;           // 0..1  (M half)
    const int wn = wave & 3;            // 0..3  (N quarter)

    // XCD-aware swizzle of the 384-block grid (3 col x 128 row tiles)
    const int flat = blockIdx.y * 3 + blockIdx.x;
    const int xcd = flat & 7;
    const int sub = flat >> 3;          // 0..47
    const int ct  = sub % 3;
    const int rt  = xcd * 16 + sub / 3; // 0..127
    const int row0 = rt * 256;
    const int col0 = ct * 256;

    __shared__ v8h As[4][1024];   // 4 slots x (256 rows x 4 k-chunks) = 64KB
    __shared__ v8h Bs[4][1024];   // 64KB

    v4f acc[8][4];
    #pragma unroll
    for (int i = 0; i < 8; ++i)
        #pragma unroll
        for (int j = 0; j < 4; ++j)
            acc[i][j] = (v4f){0.f, 0.f, 0.f, 0.f};

    const v8h* gA = (const v8h*)A;     // row stride 96 chunks
    const v8h* gB = (const v8h*)BT;

    // staging: thread t covers row (t>>2) [+128 on 2nd load], k-chunk (t&3)
    const size_t gaBase = (size_t)(row0 + (t>>2))*96 + (t&3);
    const size_t gbBase = (size_t)(col0 + (t>>2))*96 + (t&3);
    char* ldsA0 = (char*)As + t*16;
    char* ldsB0 = (char*)Bs + t*16;

    const int q = lane >> 4;           // k-sub-chunk 0..3 (8 k each)
    const int m = lane & 15;
    const int arow4 = (wm*128 + m)*4 + q;   // + mi*64
    const int brow4 = (wn*64  + m)*4 + q;   // + ni*64

    v8h af[4], bf[4];

#define STG_A(slot, tile, kc) do {                                             \
    GLDS16(ldsA0 + (slot)*16384,        gA + gaBase + (tile)*8 + (kc)*4);      \
    GLDS16(ldsA0 + (slot)*16384 + 8192, gA + gaBase + (tile)*8 + (kc)*4 + 12288); \
} while (0)
#define STG_B(slot, tile, kc) do {                                             \
    GLDS16(ldsB0 + (slot)*16384,        gB + gbBase + (tile)*8 + (kc)*4);      \
    GLDS16(ldsB0 + (slot)*16384 + 8192, gB + gbBase + (tile)*8 + (kc)*4 + 12288); \
} while (0)
#define RD_A_LO(s) { _Pragma("unroll") for (int i_=0;i_<4;++i_) af[i_] = As[s][arow4 + i_*64]; }
#define RD_A_HI(s) { _Pragma("unroll") for (int i_=0;i_<4;++i_) af[i_] = As[s][arow4 + (i_+4)*64]; }
#define RD_B(s)    { _Pragma("unroll") for (int i_=0;i_<4;++i_) bf[i_] = Bs[s][brow4 + i_*64]; }
#define MFMA_Q(mo) do {                                                        \
    __builtin_amdgcn_s_setprio(1);                                             \
    _Pragma("unroll")                                                          \
    for (int mi_=0; mi_<4; ++mi_)                                              \
        _Pragma("unroll")                                                      \
        for (int ni_=0; ni_<4; ++ni_)                                          \
            acc[(mo)+mi_][ni_] = __builtin_amdgcn_mfma_f32_16x16x32_f16(       \
                af[mi_], bf[ni_], acc[(mo)+mi_][ni_], 0, 0, 0);                \
    __builtin_amdgcn_s_setprio(0);                                             \
} while (0)

    // prologue: tile0 (both halves) + tile1 k0 -> slots 0,1,2
    STG_A(0, 0, 0); STG_B(0, 0, 0);
    STG_A(1, 0, 1); STG_B(1, 0, 1);
    STG_A(2, 1, 0); STG_B(2, 1, 0);
    VMCNT(6);                       // tile0 fully landed; 3 halves in flight
    BAR();

    // steady state: tiles 0..9 (K-tile pair per u). Even T reads slots {0,1},
    // stages slots {3,0}; odd T reads {2,3}, stages {1,2}.
    for (int u = 0; u < 5; ++u) {
        const int T = 2*u;
        // ---- even tile T ----
        RD_A_LO(0); RD_B(0); STG_A(3, T+1, 1); BAR(); MFMA_Q(0); BAR();
        RD_A_HI(0);          STG_B(3, T+1, 1); BAR(); MFMA_Q(4); VMCNT(6); BAR();
        RD_A_LO(1); RD_B(1); STG_A(0, T+2, 0); BAR(); MFMA_Q(0); BAR();
        RD_A_HI(1);          STG_B(0, T+2, 0); BAR(); MFMA_Q(4); VMCNT(6); BAR();
        // ---- odd tile T+1 ----
        RD_A_LO(2); RD_B(2); STG_A(1, T+2, 1); BAR(); MFMA_Q(0); BAR();
        RD_A_HI(2);          STG_B(1, T+2, 1); BAR(); MFMA_Q(4); VMCNT(6); BAR();
        RD_A_LO(3); RD_B(3); STG_A(2, T+3, 0); BAR(); MFMA_Q(0); BAR();
        RD_A_HI(3);          STG_B(2, T+3, 0); BAR(); MFMA_Q(4); VMCNT(6); BAR();
    }

    // tail: tile 10 (stages only tile11 k1), tile 11 (no stages)
    RD_A_LO(0); RD_B(0); STG_A(3, 11, 1); BAR(); MFMA_Q(0); BAR();
    RD_A_HI(0);          STG_B(3, 11, 1); BAR(); MFMA_Q(4); VMCNT(6); BAR();
    RD_A_LO(1); RD_B(1);                  BAR(); MFMA_Q(0); BAR();
    RD_A_HI(1);                           BAR(); MFMA_Q(4); VMCNT(4); BAR();
    RD_A_LO(2); RD_B(2);                  BAR(); MFMA_Q(0); BAR();
    RD_A_HI(2);                           BAR(); MFMA_Q(4); VMCNT(0); BAR();
    RD_A_LO(3); RD_B(3);                  BAR(); MFMA_Q(0); BAR();
    RD_A_HI(3);                           BAR(); MFMA_Q(4);

#undef STG_A
#undef STG_B
#undef RD_A_LO
#undef RD_A_HI
#undef RD_B
#undef MFMA_Q

    // Epilogue. C/D layout: col = lane&15, row = (lane>>4)*4 + reg.
    #pragma unroll
    for (int mi = 0; mi < 8; ++mi) {
        #pragma unroll
        for (int i = 0; i < 4; ++i) {
            const int grow = row0 + wm*128 + mi*16 + q*4 + i;
            #pragma unroll
            for (int ni = 0; ni < 4; ++ni) {
                const int gcol = col0 + wn*64 + ni*16 + m;
                float v = acc[mi][ni][i] + bias[gcol];
                if (MODE == 0) {
                    const int s = grow & 4095;
                    if (gcol >= 72 && gcol < 456)
                        v *= rope[s*64 + ((gcol - 72) & 63)];
                    else if (gcol >= 480 && gcol < 608)
                        v *= rope[s*64 + ((gcol - 480) & 63)];
                }
                C[(size_t)grow*768 + gcol] = v;
            }
        }
    }
}

// ---------------------------------------------------------------------------
// Factorized per-position attention (rope already in P). 8 positions per
// 256-thread block. O fp16, layout [b][h][s][d].
// ---------------------------------------------------------------------------
__global__ __launch_bounds__(256) void tpa_attn_f(
    const float* __restrict__ P,
    _Float16* __restrict__ O)
{
    const int t = threadIdx.x;
    const int pos0 = blockIdx.x * 8;

    __shared__ float proj[8][772];   // row pad 768->772: de-bank positions
    __shared__ float Gs[8][12];
    __shared__ float sc[8][160];     // 12 rows x stride 13
    __shared__ float cs[8][24];

    // load 8 P-rows (float4)
    const float4* gp = (const float4*)P;
    for (int i = t; i < 8*192; i += 256) {
        int p = i / 192, c = i - p*192;
        float4 u = gp[(size_t)(pos0 + p)*192 + c];
        proj[p][c*4+0] = u.x; proj[p][c*4+1] = u.y;
        proj[p][c*4+2] = u.z; proj[p][c*4+3] = u.w;
    }
    __syncthreads();

    // Gram matrix: 8 pos x 12 (r,r') pairs
    if (t < 96) {
        int p = t / 12, u = t - (t/12)*12, r = u >> 1, r2 = u & 1;
        const float* bq = &proj[p][72  + r*64];
        const float* bk = &proj[p][480 + r2*64];
        const int ph = (r*8 + r2*16) & 63;   // stagger start to spread banks
        float acc = 0.f;
        for (int i = 0; i < 64; ++i) {
            int d = (i + ph) & 63;
            acc = fmaf(bq[d], bk[d], acc);
        }
        Gs[p][u] = acc * 0.125f;
    }
    __syncthreads();

    // scores: 8 pos x 144 (h,g)
    for (int i = t; i < 8*144; i += 256) {
        int p = i / 144, v = i - p*144, h = v / 12, g = v - (v/12)*12;
        float s = 0.f;
        #pragma unroll
        for (int r = 0; r < RQ; ++r) {
            float mg = fmaf(Gs[p][r*2+1], proj[p][468 + g],
                            Gs[p][r*2+0] * proj[p][456 + g]);
            s = fmaf(proj[p][r*12 + h], mg, s);
        }
        sc[p][h*13 + g] = s;
    }
    __syncthreads();

    // softmax over g: 96 rows
    if (t < 96) {
        int p = t / 12, h = t - (t/12)*12;
        float* row = &sc[p][h*13];
        float mx = -1e30f;
        #pragma unroll
        for (int g = 0; g < NH; ++g) mx = fmaxf(mx, row[g]);
        float sum = 0.f;
        #pragma unroll
        for (int g = 0; g < NH; ++g) { float e = __expf(row[g]-mx); row[g] = e; sum += e; }
        float inv = 1.0f / sum;
        #pragma unroll
        for (int g = 0; g < NH; ++g) row[g] *= inv;
    }
    __syncthreads();

    // c[h,r'] = attn . av^T : 8 pos x 24
    if (t < 192) {
        int p = t / 24, u = t - (t/24)*24, h = u >> 1, r2 = u & 1;
        float acc = 0.f;
        #pragma unroll
        for (int g = 0; g < NH; ++g)
            acc = fmaf(sc[p][h*13+g], proj[p][608 + r2*12 + g], acc);
        cs[p][h*2 + r2] = acc;
    }
    __syncthreads();

    // out: 8 pos x 768, d fastest for coalesced fp16 stores
    for (int i = t; i < 8*768; i += 256) {
        int p = i / 768, j = i - p*768, h = j >> 6, d = j & 63;
        int pos = pos0 + p, b = pos >> 12, s = pos & 4095;
        float val = fmaf(cs[p][h*2+1], proj[p][632 + 64 + d],
                         cs[p][h*2+0] * proj[p][632 + d]);
        O[(((size_t)b*NH + h)*SEQ + s)*DK + d] = (_Float16)val;
    }
}

extern "C" void kernel_launch(void* const* d_in, const int* in_sizes, int n_in,
                              void* d_out, int out_size, void* d_ws, size_t ws_size,
                              hipStream_t stream) {
    const float* x    = (const float*)d_in[0];
    const float* rope = (const float*)d_in[1];
    const float* Waq  = (const float*)d_in[2];
    const float* baq  = (const float*)d_in[3];
    const float* Wbq  = (const float*)d_in[4];
    const float* bbq  = (const float*)d_in[5];
    const float* Wak  = (const float*)d_in[6];
    const float* bak  = (const float*)d_in[7];
    const float* Wbk  = (const float*)d_in[8];
    const float* bbk  = (const float*)d_in[9];
    const float* Wav  = (const float*)d_in[10];
    const float* bav  = (const float*)d_in[11];
    const float* Wbv  = (const float*)d_in[12];
    const float* bbv  = (const float*)d_in[13];
    const float* Wo   = (const float*)d_in[14];
    const float* bo   = (const float*)d_in[15];

    // ws layout (total ~52.7 MB): fp16 weights + fp16 O
    char* ws = (char*)d_ws;
    _Float16* WcatT = (_Float16*)(ws);                 // 1,179,648 B
    _Float16* WoT   = (_Float16*)(ws + 1179648);       // 1,179,648 B
    float*    bcat  = (float*)(ws + 2359296);          // 3,072 B
    _Float16* O     = (_Float16*)(ws + 2363392);       // 50,331,648 B

    // P (fp32, 32768x768) lives in d_out; fully consumed by tpa_attn_f
    // before the final GEMM overwrites d_out.
    float* P = (float*)d_out;

    // Xh (fp16 x, 48 MB) time-shares the O region.
    _Float16* Xh = O;

    repack<<<768, 256, 0, stream>>>(Waq, baq, Wbq, bbq, Wak, bak, Wbk, bbk,
                                    Wav, bav, Wbv, bbv, Wo, WcatT, WoT, bcat);

    convert_x<<<1024, 256, 0, stream>>>((const float4*)x, (v8h*)Xh);

    dim3 gg(3, 128);
    mfma_gemm<0><<<gg, 512, 0, stream>>>(Xh, WcatT, bcat, rope, P);

    tpa_attn_f<<<NPOS/8, 256, 0, stream>>>(P, O);

    mfma_gemm<1><<<gg, 512, 0, stream>>>(O, WoT, bo, nullptr, (float*)d_out);
}